// Round 13
// baseline (55.841 us; speedup 1.0000x reference)
//
#include <hip/hip_runtime.h>
#include <hip/hip_bf16.h>

#define B_   32
#define N_   2048
#define VD_  512
#define AD_  128
#define SD_  128
#define TM   32
#define THREADS 128

typedef __attribute__((ext_vector_type(8))) short short8;
typedef __attribute__((ext_vector_type(4))) float f32x4;

// ws layout (ushort element offsets) for fragment-packed bf16 weights.
// Packing: for W[C][K], frag (n,kc,l,e): dst[((n*(K/32)+kc)*64+l)*8+e] = W[n*16+(l&15)][kc*32+(l>>4)*8+e]
#define WOFF_VFC 0        // C=128,K=512: 65536
#define WOFF_AFC 65536    // C=128,K=128: 16384
#define WOFF_AM  81920    // C=128,K=128: 16384
#define WOFF_V   98304    // C=64, K=128: 8192
#define WOFF_U   106496   // C=64, K=128: 8192
#define WTOT     114688   // ushorts = 229376 bytes; zpart (bf16) follows

__device__ __forceinline__ float sigmoidf_(float x) { return 1.0f / (1.0f + __expf(-x)); }

__device__ __forceinline__ ushort f2bf(float x) {   // RNE
    union { float f; unsigned int i; } v; v.f = x;
    unsigned int r = v.i + 0x7FFFu + ((v.i >> 16) & 1u);
    return (ushort)(r >> 16);
}
__device__ __forceinline__ float bf2f(ushort u) {
    union { unsigned int i; float f; } v; v.i = ((unsigned int)u) << 16; return v.f;
}
// Xbuf swizzle: ushort [32][128], XOR on 16B chunks
__device__ __forceinline__ int swz(int row, int k, int ldk) {
    return row * ldk + (k ^ ((row & 7) << 3));
}
// A-ring swizzle: f32 [32][32], (row, 16B-chunk c in 0..7) -> f32 index
__device__ __forceinline__ int fswz(int row, int c) {
    return row * 32 + ((c ^ (row & 7)) << 2);
}
// 8x f32 -> 8x bf16 packed convert (RNE)
__device__ __forceinline__ short8 pack8(float4 x, float4 y) {
    union { unsigned int u[4]; short8 s; } o;
    asm("v_cvt_pk_bf16_f32 %0, %1, %2" : "=v"(o.u[0]) : "v"(x.x), "v"(x.y));
    asm("v_cvt_pk_bf16_f32 %0, %1, %2" : "=v"(o.u[1]) : "v"(x.z), "v"(x.w));
    asm("v_cvt_pk_bf16_f32 %0, %1, %2" : "=v"(o.u[2]) : "v"(y.x), "v"(y.y));
    asm("v_cvt_pk_bf16_f32 %0, %1, %2" : "=v"(o.u[3]) : "v"(y.z), "v"(y.w));
    return o.s;
}
template<int N> __device__ __forceinline__ void vm_wait() {
    if constexpr (N == 0) asm volatile("s_waitcnt vmcnt(0)" ::: "memory");
    else asm volatile("s_waitcnt vmcnt(2)" ::: "memory");
}
// barrier that does NOT drain vmcnt (2-wave block -> cheap)
__device__ __forceinline__ void lds_sync() {
    asm volatile("s_waitcnt lgkmcnt(0)" ::: "memory");
    __builtin_amdgcn_s_barrier();
    __builtin_amdgcn_sched_barrier(0);
}

// ---- weight pre-conversion + fragment packing ----
__global__ __launch_bounds__(256)
void cvt_weights(const float* __restrict__ vfc, const float* __restrict__ afc,
                 const float* __restrict__ am,  const float* __restrict__ Vw,
                 const float* __restrict__ Uw,  ushort* __restrict__ dst)
{
    int f = blockIdx.x * 256 + threadIdx.x;
    if (f >= WTOT / 8) return;
    int e0 = f * 8;
    const float* src; int base, K;
    if      (e0 < WOFF_AFC) { src = vfc; base = WOFF_VFC; K = 512; }
    else if (e0 < WOFF_AM)  { src = afc; base = WOFF_AFC; K = 128; }
    else if (e0 < WOFF_V)   { src = am;  base = WOFF_AM;  K = 128; }
    else if (e0 < WOFF_U)   { src = Vw;  base = WOFF_V;   K = 128; }
    else                    { src = Uw;  base = WOFF_U;   K = 128; }
    int lf = f - base / 8;
    int l = lf & 63, rem = lf >> 6;
    int NK = K / 32;
    int kc = rem % NK, n = rem / NK;
    int tc = l & 15, g4 = l >> 4;
    const float* sp = src + (size_t)(n * 16 + tc) * K + kc * 32 + g4 * 8;
    float4 x = ((const float4*)sp)[0], y = ((const float4*)sp)[1];
    short8 o = pack8(x, y);
    *(short8*)(dst + e0) = o;
}

// Grid: 32 b x 64 tiles = 2048 blocks, 128 threads (2 waves: wc = wid).
// Each block owns 32 tokens; A staged via gload_lds depth-2 ring (3 x 4KB);
// B direct to registers (L2-hot packed frags). Barrier domain = 2 waves only ->
// 8 independent pipelines per CU. LDS 20KB -> 8 blocks/CU.
__global__ __launch_bounds__(THREADS, 4)
void fused_mil(const float* __restrict__ vfeat, const float* __restrict__ afeat,
               const ushort* __restrict__ wsW,
               const float* __restrict__ afc_b, const float* __restrict__ am_b,
               const float* __restrict__ vfc_b,
               const float* __restrict__ V_b,   const float* __restrict__ U_b,
               const float* __restrict__ W_w,   const float* __restrict__ W_b,
               float* __restrict__ s_out, ushort* __restrict__ zpart)
{
    __shared__ __align__(16) float  Ar[3][TM * 32];   // 12 KB A-ring
    __shared__ __align__(16) ushort Xbuf[TM * 128];   // 8 KB: ax -> gate -> ffeat

    float* sPb = (float*)Ar;          // [2][32] score partials (alias; post-stream only)
    float* sSb = sPb + 64;            // [32]

    const int tid  = threadIdx.x;
    const int bx   = blockIdx.x;
    const int b    = bx >> 6;
    const int tok0 = (bx & 63) * TM;
    const int wid  = tid >> 6;        // = wc (0/1)
    const int lane = tid & 63;
    const int t16  = lane & 15;
    const int g4   = lane >> 4;
    const int wc   = wid;

    const float* afeat_t = afeat + ((size_t)b * N_ + tok0) * AD_;
    const float* vfeat_t = vfeat + ((size_t)b * N_ + tok0) * VD_;

    f32x4 accC[2][4], accA[2][4];
    #pragma unroll
    for (int m = 0; m < 2; ++m)
        #pragma unroll
        for (int n = 0; n < 4; ++n) { accC[m][n] = (f32x4)0.0f; accA[m][n] = (f32x4)0.0f; }

    short8 pb[4];

    // issue the A-DMA for stream chunk t into ring buffer dst (2 instrs/wave)
    #define ISSUE_A(t, dst)                                                             \
        do {                                                                            \
            const float* _src; int _ldK, _kcol;                                         \
            if ((t) < 16) { _src = vfeat_t; _ldK = VD_; _kcol = (t) * 32; }             \
            else          { _src = afeat_t; _ldK = AD_; _kcol = ((t) - 16) * 32; }      \
            _Pragma("unroll")                                                           \
            for (int _i = 0; _i < 2; ++_i) {                                            \
                int _s   = (_i * 2 + wid) * 64 + lane;                                  \
                int _row = _s >> 3, _j = (_s & 7) ^ (_row & 7);                         \
                const float* _gp = _src + (size_t)_row * _ldK + _kcol + _j * 4;         \
                float* _lp = (dst) + (_i * 2 + wid) * 256;                              \
                __builtin_amdgcn_global_load_lds(                                       \
                    (const __attribute__((address_space(1))) void*)_gp,                 \
                    (__attribute__((address_space(3))) void*)_lp, 16, 0, 0);            \
            }                                                                           \
        } while (0)

    // load the 4 B n-tile fragments for chunk t into pb (plain loads -> VGPR)
    #define LOAD_B(t)                                                                   \
        do {                                                                            \
            if ((t) < 16) {                                                             \
                const ushort* _bp = wsW + WOFF_VFC + ((size_t)(4 * wc) * 16 + (t)) * 512 + lane * 8; \
                _Pragma("unroll")                                                       \
                for (int _n = 0; _n < 4; ++_n)                                          \
                    pb[_n] = *(const short8*)(_bp + (size_t)_n * 16 * 512);             \
            } else {                                                                    \
                const ushort* _bp = wsW + WOFF_AFC + ((size_t)(4 * wc) * 4 + (t) - 16) * 512 + lane * 8; \
                _Pragma("unroll")                                                       \
                for (int _n = 0; _n < 4; ++_n)                                          \
                    pb[_n] = *(const short8*)(_bp + (size_t)_n * 4 * 512);              \
            }                                                                           \
        } while (0)

    // prologue: B(0) first (FIFO-oldest), then A(0), A(1)
    LOAD_B(0);
    ISSUE_A(0, Ar[0]);
    ISSUE_A(1, Ar[1]);

    #pragma unroll
    for (int k = 0; k < 20; ++k) {
        if (k < 19) vm_wait<2>();      // A(k)+B(k) landed; A(k+1) x2 outstanding
        else        vm_wait<0>();
        asm volatile("s_waitcnt lgkmcnt(0)" ::: "memory");
        __builtin_amdgcn_s_barrier();
        __builtin_amdgcn_sched_barrier(0);
        if (k + 2 < 20) ISSUE_A(k + 2, Ar[(k + 2) % 3]);
        // compute chunk k: A-frags from ring, B from pb
        {
            const float* Ab = Ar[k % 3];
            float4 x0 = *(const float4*)&Ab[fswz(t16,      2 * g4)];
            float4 y0 = *(const float4*)&Ab[fswz(t16,      2 * g4 + 1)];
            float4 x1 = *(const float4*)&Ab[fswz(t16 + 16, 2 * g4)];
            float4 y1 = *(const float4*)&Ab[fswz(t16 + 16, 2 * g4 + 1)];
            short8 a0 = pack8(x0, y0), a1 = pack8(x1, y1);
            f32x4 (&acc)[2][4] = (k < 16) ? accC : accA;
            #pragma unroll
            for (int n = 0; n < 4; ++n) {
                acc[0][n] = __builtin_amdgcn_mfma_f32_16x16x32_bf16(a0, pb[n], acc[0][n], 0, 0, 0);
                acc[1][n] = __builtin_amdgcn_mfma_f32_16x16x32_bf16(a1, pb[n], acc[1][n], 0, 0, 0);
            }
        }
        if (k + 1 < 20) LOAD_B(k + 1);   // after MFMAs consumed pb
    }
    #undef ISSUE_A
    #undef LOAD_B

    lds_sync();                           // all staging retired (alias safety)

    // ---- ax = relu(accA + afc_b) -> Xbuf ----
    #pragma unroll
    for (int n = 0; n < 4; ++n) {
        int c = 64 * wc + 16 * n + t16;
        float bias = afc_b[c];
        #pragma unroll
        for (int m = 0; m < 2; ++m)
            #pragma unroll
            for (int r = 0; r < 4; ++r) {
                int row = 16 * m + 4 * g4 + r;
                Xbuf[swz(row, c, 128)] = f2bf(fmaxf(accA[m][n][r] + bias, 0.0f));
            }
    }
    lds_sync();                           // ax visible to both waves

    // ---- gate = sigmoid(ax @ am_w^T + am_b) ----
    f32x4 accB[2][4];
    #pragma unroll
    for (int m = 0; m < 2; ++m)
        #pragma unroll
        for (int n = 0; n < 4; ++n) accB[m][n] = (f32x4)0.0f;
    #pragma unroll
    for (int kc = 0; kc < 4; ++kc) {
        int kk = kc * 32 + g4 * 8;
        short8 a0 = *(const short8*)&Xbuf[swz(t16,      kk, 128)];
        short8 a1 = *(const short8*)&Xbuf[swz(t16 + 16, kk, 128)];
        #pragma unroll
        for (int n = 0; n < 4; ++n) {
            short8 bmat = *(const short8*)(wsW + WOFF_AM + ((size_t)((4 * wc + n) * 4 + kc)) * 512 + lane * 8);
            accB[0][n] = __builtin_amdgcn_mfma_f32_16x16x32_bf16(a0, bmat, accB[0][n], 0, 0, 0);
            accB[1][n] = __builtin_amdgcn_mfma_f32_16x16x32_bf16(a1, bmat, accB[1][n], 0, 0, 0);
        }
    }
    lds_sync();                           // all ax reads done

    // stash gate bf16 into own Xbuf cells (thread-private)
    #pragma unroll
    for (int n = 0; n < 4; ++n) {
        int c = 64 * wc + 16 * n + t16;
        float bias = am_b[c];
        #pragma unroll
        for (int m = 0; m < 2; ++m)
            #pragma unroll
            for (int r = 0; r < 4; ++r) {
                int row = 16 * m + 4 * g4 + r;
                Xbuf[swz(row, c, 128)] = f2bf(sigmoidf_(accB[m][n][r] + bias));
            }
    }

    // ---- ffeat = relu(vo1 + vfc_b) * (1 + gate) -> Xbuf ----
    #pragma unroll
    for (int n = 0; n < 4; ++n) {
        int c = 64 * wc + 16 * n + t16;
        float vb = vfc_b[c];
        #pragma unroll
        for (int m = 0; m < 2; ++m)
            #pragma unroll
            for (int r = 0; r < 4; ++r) {
                int row = 16 * m + 4 * g4 + r;
                float g   = bf2f(Xbuf[swz(row, c, 128)]);
                float vo1 = fmaxf(accC[m][n][r] + vb, 0.0f);
                Xbuf[swz(row, c, 128)] = f2bf(vo1 * (1.0f + g));
            }
    }
    lds_sync();                           // ffeat visible

    // ---- v/u heads: n=0,1 -> V tiles 2wc+n; n=2,3 -> U same; h = 32wc+16n+t16 ----
    #pragma unroll
    for (int m = 0; m < 2; ++m)
        #pragma unroll
        for (int n = 0; n < 4; ++n) accB[m][n] = (f32x4)0.0f;
    {
        const ushort* Vp = wsW + WOFF_V;
        const ushort* Up = wsW + WOFF_U;
        #pragma unroll
        for (int kc = 0; kc < 4; ++kc) {
            int kk = kc * 32 + g4 * 8;
            short8 a0 = *(const short8*)&Xbuf[swz(t16,      kk, 128)];
            short8 a1 = *(const short8*)&Xbuf[swz(t16 + 16, kk, 128)];
            #pragma unroll
            for (int n = 0; n < 2; ++n) {
                short8 bv = *(const short8*)(Vp + ((size_t)(2 * wc + n) * 4 + kc) * 512 + lane * 8);
                short8 bu = *(const short8*)(Up + ((size_t)(2 * wc + n) * 4 + kc) * 512 + lane * 8);
                accB[0][n]     = __builtin_amdgcn_mfma_f32_16x16x32_bf16(a0, bv, accB[0][n],     0, 0, 0);
                accB[1][n]     = __builtin_amdgcn_mfma_f32_16x16x32_bf16(a1, bv, accB[1][n],     0, 0, 0);
                accB[0][n + 2] = __builtin_amdgcn_mfma_f32_16x16x32_bf16(a0, bu, accB[0][n + 2], 0, 0, 0);
                accB[1][n + 2] = __builtin_amdgcn_mfma_f32_16x16x32_bf16(a1, bu, accB[1][n + 2], 0, 0, 0);
            }
        }
    }

    // ---- score s = sum_h relu(v)*sigmoid(u)*W_w + W_b ----
    #pragma unroll
    for (int m = 0; m < 2; ++m)
        #pragma unroll
        for (int r = 0; r < 4; ++r) {
            float p = 0.0f;
            #pragma unroll
            for (int n = 0; n < 2; ++n) {
                int h = 32 * wc + 16 * n + t16;
                float vv = fmaxf(accB[m][n][r] + V_b[h], 0.0f);
                float uu = sigmoidf_(accB[m][n + 2][r] + U_b[h]);
                p = fmaf(vv * uu, W_w[h], p);
            }
            p += __shfl_xor(p, 1);
            p += __shfl_xor(p, 2);
            p += __shfl_xor(p, 4);
            p += __shfl_xor(p, 8);
            if (t16 == 0) sPb[wc * 32 + 16 * m + 4 * g4 + r] = p;
        }
    __syncthreads();
    if (tid < TM) {
        float s = sPb[tid] + sPb[32 + tid] + W_b[0];
        sSb[tid] = s;
        s_out[(size_t)b * N_ + tok0 + tid] = s;
    }
    __syncthreads();

    // ---- zpart[k] = sum_t s[t] * ffeat[t][k] (bf16 partials) ----
    {
        int k = tid;
        float z = 0.0f;
        #pragma unroll
        for (int t = 0; t < TM; ++t)
            z = fmaf(sSb[t], bf2f(Xbuf[swz(t, k, 128)]), z);
        zpart[(size_t)bx * 128 + k] = f2bf(z);
    }
}

// Grid: 32 blocks, 128 threads.
__global__ __launch_bounds__(128)
void reduce_logits(const ushort* __restrict__ zpart,
                   const float* __restrict__ cls_w, const float* __restrict__ cls_b,
                   float* __restrict__ out)
{
    __shared__ float sZ[128];
    int b = blockIdx.x, k = threadIdx.x;
    float z = 0.0f;
    #pragma unroll
    for (int t = 0; t < 64; ++t) z += bf2f(zpart[(size_t)(b * 64 + t) * 128 + k]);
    sZ[k] = z;
    __syncthreads();
    if (k < 2) {
        float acc = cls_b[k];
        for (int i = 0; i < 128; ++i) acc = fmaf(sZ[i], cls_w[k * 128 + i], acc);
        out[(size_t)B_ * N_ + b * 2 + k] = acc;
    }
}

extern "C" void kernel_launch(void* const* d_in, const int* in_sizes, int n_in,
                              void* d_out, int out_size, void* d_ws, size_t ws_size,
                              hipStream_t stream) {
    const float* vfeat = (const float*)d_in[0];
    const float* afeat = (const float*)d_in[1];
    const float* vfc_w = (const float*)d_in[2];
    const float* vfc_b = (const float*)d_in[3];
    const float* afc_w = (const float*)d_in[4];
    const float* afc_b = (const float*)d_in[5];
    const float* am_w  = (const float*)d_in[6];
    const float* am_b  = (const float*)d_in[7];
    const float* U_w   = (const float*)d_in[8];
    const float* U_b   = (const float*)d_in[9];
    const float* V_w   = (const float*)d_in[10];
    const float* V_b   = (const float*)d_in[11];
    const float* W_w   = (const float*)d_in[12];
    const float* W_b   = (const float*)d_in[13];
    const float* cls_w = (const float*)d_in[14];
    const float* cls_b = (const float*)d_in[15];

    float* out    = (float*)d_out;
    ushort* wsW   = (ushort*)d_ws;                             // 229376 B packed bf16 weights
    ushort* zpart = (ushort*)((char*)d_ws + (size_t)WTOT * 2); // 2048*128*2 = 512 KB

    cvt_weights<<<dim3((WTOT / 8 + 255) / 256), dim3(256), 0, stream>>>(vfc_w, afc_w, am_w, V_w, U_w, wsW);
    fused_mil<<<dim3(B_ * 64), dim3(THREADS), 0, stream>>>(
        vfeat, afeat, wsW, afc_b, am_b, vfc_b, V_b, U_b, W_w, W_b, out, zpart);
    reduce_logits<<<dim3(B_), dim3(128), 0, stream>>>(zpart, cls_w, cls_b, out);
}